// Round 1
// baseline (373.343 us; speedup 1.0000x reference)
//
#include <hip/hip_runtime.h>

#define NSTATES 64

// Viterbi ACS: one-hot gather + branch metric + pairwise max/argmax.
// 16 lanes per row, 4 states per lane. Per-lane edge constants hoisted out
// of the grid-stride row loop. All fp32 roundings are forced (weights are
// exactly {0,1}, llr signs exactly +-1) => bit-identical to numpy ref.
__global__ __launch_bounds__(256) void viterbi_acs_kernel(
    const float* __restrict__ in_prob,   // [B, 64]
    const float* __restrict__ llrs,      // [B, 2]
    const float* __restrict__ s2e,       // [64, 128]
    const float* __restrict__ mask,      // [64, 128]
    const float* __restrict__ l2e,       // [2, 128]
    float* __restrict__ out_max,         // [B, 64]
    float* __restrict__ out_ind,         // [B, 64] (0.0f / 1.0f)
    int batch)
{
    const int tid = blockIdx.x * blockDim.x + threadIdx.x;
    const int c = tid & 15;              // chunk within row: states 4c..4c+3

    // Per-chunk constants (independent of row): edge weights + llr sign rows.
    float w0[4], w1[4], t00[4], t01[4], t10[4], t11[4];
#pragma unroll
    for (int j = 0; j < 4; ++j) {
        const int d  = 4 * c + j;        // destination state
        const int e0 = 2 * d;            // competing edge 0
        const int e1 = 2 * d + 1;        // competing edge 1
        const int s0 = 2 * (d & 31);     // source state of edge 0
        const int s1 = s0 + 1;           // source state of edge 1
        w0[j]  = s2e[s0 * 128 + e0] * mask[s0 * 128 + e0];
        w1[j]  = s2e[s1 * 128 + e1] * mask[s1 * 128 + e1];
        t00[j] = l2e[e0];       t01[j] = l2e[128 + e0];
        t10[j] = l2e[e1];       t11[j] = l2e[128 + e1];
    }

    const int row0       = tid >> 4;
    const int row_stride = (int)((gridDim.x * blockDim.x) >> 4);

    for (int row = row0; row < batch; row += row_stride) {
        // Lane needs in_prob[row, 8*(c&7) .. 8*(c&7)+7] (contiguous 32 B).
        const float* rp = in_prob + (size_t)row * NSTATES + (c & 7) * 8;
        const float4 va = *(const float4*)(rp);
        const float4 vb = *(const float4*)(rp + 4);
        const float v[8] = {va.x, va.y, va.z, va.w, vb.x, vb.y, vb.z, vb.w};

        const float2 lp = *(const float2*)(llrs + (size_t)row * 2);

        float4 mv, iv;
        float* mp = &mv.x;
        float* ip = &iv.x;
#pragma unroll
        for (int j = 0; j < 4; ++j) {
            const float bm0 = lp.x * t00[j] + lp.y * t01[j];
            const float bm1 = lp.x * t10[j] + lp.y * t11[j];
            const float x0  = v[2 * j]     * w0[j] + bm0;
            const float x1  = v[2 * j + 1] * w1[j] + bm1;
            mp[j] = fmaxf(x0, x1);
            ip[j] = (x1 > x0) ? 1.0f : 0.0f;   // argmax, first index wins ties
        }

        float* om = out_max + (size_t)row * NSTATES + c * 4;
        float* oi = out_ind + (size_t)row * NSTATES + c * 4;
        *(float4*)om = mv;
        *(float4*)oi = iv;
    }
}

extern "C" void kernel_launch(void* const* d_in, const int* in_sizes, int n_in,
                              void* d_out, int out_size, void* d_ws, size_t ws_size,
                              hipStream_t stream) {
    const float* in_prob = (const float*)d_in[0];
    const float* llrs    = (const float*)d_in[1];
    const float* s2e     = (const float*)d_in[2];
    const float* mask    = (const float*)d_in[3];
    const float* l2e     = (const float*)d_in[4];

    const int batch = in_sizes[0] / NSTATES;          // 524288
    float* out_max = (float*)d_out;                   // [B,64]
    float* out_ind = (float*)d_out + (size_t)batch * NSTATES;

    const int block = 256;
    const int grid  = 2048;   // 8 blocks/CU; 16 rows per thread grid-stride
    viterbi_acs_kernel<<<grid, block, 0, stream>>>(
        in_prob, llrs, s2e, mask, l2e, out_max, out_ind, batch);
}